// Round 1
// baseline (86543.439 us; speedup 1.0000x reference)
//
#include <hip/hip_runtime.h>
#include <cstdint>
#include <cstddef>

// MirrorLM forward, fp32 end-to-end.
//  B=32 T=2048 V=50257 D=H=512 NH=2 HD=256
// Pipeline:
//  embed -> [KV gemm: k_sum/kv_sum via atomics] -> [Q gemm: num/den via atomics]
//  -> [GATE gemm: x1 = gate*r + (1-gate)*x0] -> [LIN gemms: xin, xz]
//  -> persistent 2048-step scan (256 WGs, 2 h-columns each, device barrier)
//  -> pred_error_norm, LayerNorm, LM-head gemm.

#define B_ 32
#define T_ 2048
#define V_ 50257
#define D_ 512
#define H_ 512
#define NH_ 2
#define BT_ (B_*T_)   // 65536

// ---- workspace layout (bytes). Requires ~404 MB of d_ws. ----
#define OFF_X0    ((size_t)0)                          // [BT][512] f32, later reused as xin
#define OFF_X1    (OFF_X0 + (size_t)BT_*D_*4)          // [BT][512] f32 (gated x)
#define OFF_XZ    (OFF_X1 + (size_t)BT_*D_*4)          // [BT][512] f32 (xz)
#define OFF_SMALL (OFF_XZ + (size_t)BT_*D_*4)
#define OFF_RBUF  (OFF_SMALL)                          // [BT][NH][2] f32 num/den = 1 MB
#define OFF_KSUM  (OFF_RBUF + (size_t)BT_*NH_*2*4)     // [B][512]
#define OFF_KVSUM (OFF_KSUM + (size_t)B_*D_*4)         // [B][512]
#define OFF_HA    (OFF_KVSUM + (size_t)B_*D_*4)        // h buffer A: [512][32] (j-major)
#define OFF_HB    (OFF_HA + (size_t)H_*B_*4)           // h buffer B
#define OFF_BAR   (OFF_HB + (size_t)H_*B_*4)           // barrier ints (256 B)
#define OFF_HLN   (OFF_BAR + 256)                      // LN'd h: [32][512]
#define ZERO_F4   ((OFF_BAR + 256 - OFF_SMALL) / 16)   // float4 count to zero

__device__ __forceinline__ float phi_f(float x) {           // elu(x)+1
  return x > 0.f ? x + 1.f : expf(x);
}
__device__ __forceinline__ float sigm_f(float x) {
  return 1.f / (1.f + expf(-x));
}

// ---------------- zero small state ----------------
__global__ __launch_bounds__(256) void zero_k(float4* __restrict__ p, int n) {
  int i = blockIdx.x * 256 + threadIdx.x;
  if (i < n) p[i] = make_float4(0.f, 0.f, 0.f, 0.f);
}

// ---------------- embedding gather ----------------
__global__ __launch_bounds__(256) void embed_k(const int* __restrict__ ids,
                                               const float* __restrict__ emb,
                                               float* __restrict__ x0) {
  size_t idx = (size_t)blockIdx.x * 256 + threadIdx.x;   // over BT*128 float4
  int row = (int)(idx >> 7), c = (int)(idx & 127);
  int id = ids[row];
  ((float4*)x0)[idx] = ((const float4*)emb)[(size_t)id * 128 + c];
}

// ---------------- tiled fp32 GEMM, Y = X @ W^T, 64x64x32 tiles ----------------
// MODE 0: KV   -> phi(X@Wk^T), X@Wv^T; atomicAdd k_sum/kv_sum (reduce over t)
// MODE 1: Q    -> phi(X@Wq^T); atomicAdd num/den partials vs kv_sum/k_sum
// MODE 2: GATE -> gate=sigmoid(X@Wg^T+bg); x1 = gate*r + (1-gate)*x0
// MODE 3: LIN  -> X@W^T + bias
template<int MODE>
__global__ __launch_bounds__(256, 2) void gemm_k(
    const float* __restrict__ X, const float* __restrict__ W0,
    const float* __restrict__ W1, const float* __restrict__ bias,
    const float* __restrict__ aux0, const float* __restrict__ aux1,
    float* __restrict__ out0, float* __restrict__ out1) {
  constexpr bool KV = (MODE == 0);
  __shared__ float Xs[32][68];
  __shared__ float Ws[32][68];
  __shared__ float Ws2[KV ? 32 : 1][68];
  const int tid = threadIdx.x;
  const int m0 = blockIdx.x * 64, n0 = blockIdx.y * 64;
  const int tm = tid >> 4, tn = tid & 15;
  const int lr = tid >> 3;            // staging row 0..31
  const int lc = (tid & 7) * 4;       // staging k offset
  float acc[4][4] = {};
  float acc2[KV ? 4 : 1][4] = {};

  for (int k0 = 0; k0 < 512; k0 += 32) {
    const float4 xa = *(const float4*)&X[(size_t)(m0 + lr) * 512 + k0 + lc];
    const float4 xb = *(const float4*)&X[(size_t)(m0 + 32 + lr) * 512 + k0 + lc];
    const float4 wa = *(const float4*)&W0[(size_t)(n0 + lr) * 512 + k0 + lc];
    const float4 wb = *(const float4*)&W0[(size_t)(n0 + 32 + lr) * 512 + k0 + lc];
    float4 va, vb;
    if constexpr (KV) {
      va = *(const float4*)&W1[(size_t)(n0 + lr) * 512 + k0 + lc];
      vb = *(const float4*)&W1[(size_t)(n0 + 32 + lr) * 512 + k0 + lc];
    }
    __syncthreads();
    Xs[lc+0][lr] = xa.x; Xs[lc+1][lr] = xa.y; Xs[lc+2][lr] = xa.z; Xs[lc+3][lr] = xa.w;
    Xs[lc+0][lr+32] = xb.x; Xs[lc+1][lr+32] = xb.y; Xs[lc+2][lr+32] = xb.z; Xs[lc+3][lr+32] = xb.w;
    Ws[lc+0][lr] = wa.x; Ws[lc+1][lr] = wa.y; Ws[lc+2][lr] = wa.z; Ws[lc+3][lr] = wa.w;
    Ws[lc+0][lr+32] = wb.x; Ws[lc+1][lr+32] = wb.y; Ws[lc+2][lr+32] = wb.z; Ws[lc+3][lr+32] = wb.w;
    if constexpr (KV) {
      Ws2[lc+0][lr] = va.x; Ws2[lc+1][lr] = va.y; Ws2[lc+2][lr] = va.z; Ws2[lc+3][lr] = va.w;
      Ws2[lc+0][lr+32] = vb.x; Ws2[lc+1][lr+32] = vb.y; Ws2[lc+2][lr+32] = vb.z; Ws2[lc+3][lr+32] = vb.w;
    }
    __syncthreads();
    #pragma unroll
    for (int kk = 0; kk < 32; ++kk) {
      float4 xv = *(const float4*)&Xs[kk][tm * 4];
      float4 wv = *(const float4*)&Ws[kk][tn * 4];
      const float* xf = (const float*)&xv;
      const float* wf = (const float*)&wv;
      #pragma unroll
      for (int i = 0; i < 4; ++i)
        #pragma unroll
        for (int j = 0; j < 4; ++j)
          acc[i][j] += xf[i] * wf[j];
      if constexpr (KV) {
        float4 wv2 = *(const float4*)&Ws2[kk][tn * 4];
        const float* w2 = (const float*)&wv2;
        #pragma unroll
        for (int i = 0; i < 4; ++i)
          #pragma unroll
          for (int j = 0; j < 4; ++j)
            acc2[i][j] += xf[i] * w2[j];
      }
    }
  }

  if constexpr (MODE == 0) {          // KV epilogue: reduce over t (rows), atomic to k_sum/kv_sum
    __syncthreads();
    float* red = &Xs[0][0];           // 128 floats scratch
    if (tid < 128) red[tid] = 0.f;
    __syncthreads();
    #pragma unroll
    for (int j = 0; j < 4; ++j) {
      float ks = 0.f, kvs = 0.f;
      #pragma unroll
      for (int i = 0; i < 4; ++i) {
        float kk_ = phi_f(acc[i][j]);
        ks += kk_;
        kvs += kk_ * acc2[i][j];
      }
      atomicAdd(&red[(tn * 4 + j) * 2 + 0], ks);
      atomicAdd(&red[(tn * 4 + j) * 2 + 1], kvs);
    }
    __syncthreads();
    if (tid < 64) {
      int b = m0 >> 11;               // row block -> batch (2048 rows per batch)
      atomicAdd(&out0[b * 512 + n0 + tid], red[tid * 2 + 0]);
      atomicAdd(&out1[b * 512 + n0 + tid], red[tid * 2 + 1]);
    }
  } else if constexpr (MODE == 1) {   // Q epilogue: num/den partials
    int b = m0 >> 11;
    float kvv[4], ksv[4];
    #pragma unroll
    for (int j = 0; j < 4; ++j) {
      int n = n0 + tn * 4 + j;
      kvv[j] = aux0[b * 512 + n];
      ksv[j] = aux1[b * 512 + n];
    }
    __syncthreads();
    float* red = &Xs[0][0];
    if (tid < 128) red[tid] = 0.f;
    __syncthreads();
    #pragma unroll
    for (int i = 0; i < 4; ++i) {
      float np = 0.f, dp = 0.f;
      #pragma unroll
      for (int j = 0; j < 4; ++j) {
        float q = phi_f(acc[i][j]);
        np += q * kvv[j];
        dp += q * ksv[j];
      }
      atomicAdd(&red[(tm * 4 + i) * 2 + 0], np);
      atomicAdd(&red[(tm * 4 + i) * 2 + 1], dp);
    }
    __syncthreads();
    if (tid < 64) {
      int m = m0 + tid, h = n0 >> 8;
      atomicAdd(&out0[((size_t)m * 2 + h) * 2 + 0], red[tid * 2 + 0]);
      atomicAdd(&out0[((size_t)m * 2 + h) * 2 + 1], red[tid * 2 + 1]);
    }
  } else if constexpr (MODE == 2) {   // GATE epilogue: x1 = g*r + (1-g)*x0
    int h = n0 >> 8;
    #pragma unroll
    for (int i = 0; i < 4; ++i) {
      int m = m0 + tm * 4 + i;
      float rn = aux0[((size_t)m * 2 + h) * 2 + 0];
      float rd = aux0[((size_t)m * 2 + h) * 2 + 1];
      float r = rn / (rd + 1e-6f);
      float4 x0v = *(const float4*)&aux1[(size_t)m * 512 + n0 + tn * 4];
      const float* xf = (const float*)&x0v;
      float4 o;
      float* of = (float*)&o;
      #pragma unroll
      for (int j = 0; j < 4; ++j) {
        int n = n0 + tn * 4 + j;
        float g = sigm_f(acc[i][j] + bias[n]);
        of[j] = g * r + (1.f - g) * xf[j];
      }
      *(float4*)&out0[(size_t)m * 512 + n0 + tn * 4] = o;
    }
  } else {                            // LIN epilogue
    #pragma unroll
    for (int i = 0; i < 4; ++i) {
      int m = m0 + tm * 4 + i;
      float4 o;
      float* of = (float*)&o;
      #pragma unroll
      for (int j = 0; j < 4; ++j)
        of[j] = acc[i][j] + bias[n0 + tn * 4 + j];
      *(float4*)&out0[(size_t)m * 512 + n0 + tn * 4] = o;
    }
  }
}

// ---------------- persistent GRU scan ----------------
// 256 WGs x 256 threads. WG bid owns h-columns j0=2*bid, j0+1 of W_h, W_zh, fast_W (LDS).
// h buffers are [512][32] (j-major). Two-level device barrier per step.
__global__ __launch_bounds__(256) void scan_k(
    const float* __restrict__ xin, const float* __restrict__ xz,
    const float* __restrict__ Wh, const float* __restrict__ Wzh,
    const float* __restrict__ fastW,
    const float* __restrict__ log_tau, const float* __restrict__ log_dt,
    float* __restrict__ hA, float* __restrict__ hB,
    int* __restrict__ bar) {
  __shared__ float w_lds[6][512];   // 0:Wh j0 1:Wh j1 2:Wzh j0 3:Wzh j1 4:fw j0 5:fw j1
  __shared__ float red[768];
  __shared__ float sums[192];
  __shared__ float s_misc[4];       // dt0 dt1 tau0 tau1
  const int tid = threadIdx.x, bid = blockIdx.x;
  const int j0 = bid * 2;
  for (int idx = tid; idx < 2048; idx += 256) {
    int r = idx >> 9, c = idx & 511;
    const float* src = (r < 2) ? Wh : Wzh;
    w_lds[r][c] = src[(size_t)(j0 + (r & 1)) * 512 + c];
  }
  for (int idx = tid; idx < 1024; idx += 256) {
    int r = idx >> 9, c = idx & 511;
    w_lds[4 + r][c] = fastW[(size_t)c * 512 + (j0 + r)];
  }
  if (tid < 2) {
    s_misc[tid] = expf(log_dt[j0 + tid]);
    s_misc[2 + tid] = expf(log_tau[j0 + tid]);
  }
  __syncthreads();
  const int lane = tid & 63, wid = tid >> 6;
  const int bq = lane & 7;                    // b-quad (4 batches)
  const int i0 = (wid * 8 + (lane >> 3)) * 16;  // this thread's k-range start
  const int jj = tid >> 5, bb = tid & 31;     // for tid<64 epilogue

  for (int t = 0; t < 2048; ++t) {
    const float* hc = (t & 1) ? hB : hA;
    float* hn = (t & 1) ? hA : hB;
    float pxin = 0.f, pxz = 0.f, hold = 0.f;
    if (tid < 64) {
      size_t off = ((size_t)bb * T_ + t) * 512 + (j0 + jj);
      pxin = xin[off];
      pxz = xz[off];
      hold = hc[(j0 + jj) * 32 + bb];
    }
    float4 hv[16];
    const float4* hc4 = (const float4*)hc;
    #pragma unroll
    for (int r = 0; r < 16; ++r) hv[r] = hc4[(i0 + r) * 8 + bq];
    float a[6][4];
    #pragma unroll
    for (int p = 0; p < 6; ++p) { a[p][0] = 0.f; a[p][1] = 0.f; a[p][2] = 0.f; a[p][3] = 0.f; }
    #pragma unroll
    for (int blk = 0; blk < 4; ++blk) {
      const float* h0 = (const float*)&hv[blk * 4 + 0];
      const float* h1 = (const float*)&hv[blk * 4 + 1];
      const float* h2 = (const float*)&hv[blk * 4 + 2];
      const float* h3 = (const float*)&hv[blk * 4 + 3];
      #pragma unroll
      for (int p = 0; p < 6; ++p) {
        float4 wp4 = *(const float4*)&w_lds[p][i0 + blk * 4];
        const float* wp = (const float*)&wp4;
        #pragma unroll
        for (int q = 0; q < 4; ++q)
          a[p][q] += wp[0] * h0[q] + wp[1] * h1[q] + wp[2] * h2[q] + wp[3] * h3[q];
      }
    }
    // reduce over k-segments: within wave (lane bits 3..5), then across 4 waves via LDS
    #pragma unroll
    for (int m = 8; m <= 32; m <<= 1)
      #pragma unroll
      for (int p = 0; p < 6; ++p)
        #pragma unroll
        for (int q = 0; q < 4; ++q)
          a[p][q] += __shfl_xor(a[p][q], m, 64);
    if ((lane >> 3) == 0) {
      #pragma unroll
      for (int p = 0; p < 6; ++p)
        #pragma unroll
        for (int q = 0; q < 4; ++q)
          red[((wid * 8 + lane) * 6 + p) * 4 + q] = a[p][q];
    }
    __syncthreads();
    if (tid < 192) {
      int p = tid >> 5, b = tid & 31;
      float s = 0.f;
      #pragma unroll
      for (int w = 0; w < 4; ++w) s += red[((w * 8 + (b >> 2)) * 6 + p) * 4 + (b & 3)];
      sums[p * 32 + b] = s;
    }
    __syncthreads();
    if (tid < 64) {
      float u = pxin + sums[jj * 32 + bb];
      float f = tanhf(u);
      float dtv = s_misc[jj], tauv = s_misc[2 + jj];
      float hl = hold + dtv * (f - tauv * hold);
      float zv = sigm_f(pxz + sums[(2 + jj) * 32 + bb]);
      float slow = (1.f - zv) * hold + zv * hl;
      hn[(j0 + jj) * 32 + bb] = slow + sums[(4 + jj) * 32 + bb];
    }
    __threadfence();
    __syncthreads();
    if (tid == 0) {
      int old = atomicAdd(&bar[bid >> 4], 1);
      if ((old & 15) == 15) atomicAdd(&bar[16], 1);
      int target = (t + 1) * 16;
      while (__hip_atomic_load(&bar[16], __ATOMIC_RELAXED, __HIP_MEMORY_SCOPE_AGENT) < target)
        __builtin_amdgcn_s_sleep(2);
    }
    __syncthreads();
    __threadfence();
  }
}

// ---------------- pred_error_norm ----------------
__global__ __launch_bounds__(256) void pred_k(const float* __restrict__ hA,
                                              const float* __restrict__ hB,
                                              float* __restrict__ out) {
  const int tid = threadIdx.x;
  float s = 0.f;
  for (int i = tid; i < H_ * B_; i += 256) {
    float d = hA[i] - hB[i];
    s += d * d;
  }
  #pragma unroll
  for (int m = 1; m < 64; m <<= 1) s += __shfl_xor(s, m, 64);
  __shared__ float r8[4];
  if ((tid & 63) == 0) r8[tid >> 6] = s;
  __syncthreads();
  if (tid == 0) out[0] = sqrtf((r8[0] + r8[1] + r8[2] + r8[3]) * (1.f / (H_ * B_)));
}

// ---------------- LayerNorm over h_last ----------------
__global__ __launch_bounds__(256) void ln_k(const float* __restrict__ hA,   // [512][32]
                                            const float* __restrict__ g,
                                            const float* __restrict__ be,
                                            float* __restrict__ hln,        // [32][512]
                                            float* __restrict__ outh) {
  const int b = blockIdx.x, tid = threadIdx.x;
  float v0 = hA[tid * 32 + b];
  float v1 = hA[(tid + 256) * 32 + b];
  float s = v0 + v1;
  #pragma unroll
  for (int m = 1; m < 64; m <<= 1) s += __shfl_xor(s, m, 64);
  __shared__ float r8[8];
  if ((tid & 63) == 0) r8[tid >> 6] = s;
  __syncthreads();
  float mu = (r8[0] + r8[1] + r8[2] + r8[3]) * (1.f / 512.f);
  float d0 = v0 - mu, d1 = v1 - mu;
  float s2 = d0 * d0 + d1 * d1;
  #pragma unroll
  for (int m = 1; m < 64; m <<= 1) s2 += __shfl_xor(s2, m, 64);
  if ((tid & 63) == 0) r8[4 + (tid >> 6)] = s2;
  __syncthreads();
  float var = (r8[4] + r8[5] + r8[6] + r8[7]) * (1.f / 512.f);
  float inv = rsqrtf(var + 1e-5f);
  float y0 = d0 * inv * g[tid] + be[tid];
  float y1 = d1 * inv * g[tid + 256] + be[tid + 256];
  hln[b * 512 + tid] = y0;
  hln[b * 512 + tid + 256] = y1;
  outh[b * 512 + tid] = y0;
  outh[b * 512 + tid + 256] = y1;
}

// ---------------- LM head: logits = hln @ Wlm^T + blm ----------------
__global__ __launch_bounds__(256, 2) void logits_k(const float* __restrict__ hln,
                                                   const float* __restrict__ Wlm,
                                                   const float* __restrict__ blm,
                                                   float* __restrict__ out) {
  __shared__ float hs[32 * 513];
  const int tid = threadIdx.x;
  for (int idx = tid; idx < 16384; idx += 256) {
    int b = idx >> 9, k = idx & 511;
    hs[b * 513 + k] = hln[idx];
  }
  __syncthreads();
  const int lane = tid & 63, w = tid >> 6;
  const int b = lane & 31, kh = lane >> 5;
  const float* hb = &hs[b * 513 + kh * 256];
  const int vbase = blockIdx.x * 64 + w * 16;
  for (int r4 = 0; r4 < 16; r4 += 4) {
    int v = vbase + r4;
    int v0i = (v + 0 < V_) ? v + 0 : V_ - 1;
    int v1i = (v + 1 < V_) ? v + 1 : V_ - 1;
    int v2i = (v + 2 < V_) ? v + 2 : V_ - 1;
    int v3i = (v + 3 < V_) ? v + 3 : V_ - 1;
    const float4* w0 = (const float4*)&Wlm[(size_t)v0i * 512 + kh * 256];
    const float4* w1 = (const float4*)&Wlm[(size_t)v1i * 512 + kh * 256];
    const float4* w2 = (const float4*)&Wlm[(size_t)v2i * 512 + kh * 256];
    const float4* w3 = (const float4*)&Wlm[(size_t)v3i * 512 + kh * 256];
    float a0 = 0.f, a1 = 0.f, a2 = 0.f, a3 = 0.f;
    #pragma unroll 8
    for (int q = 0; q < 64; ++q) {
      float h0 = hb[q * 4 + 0], h1 = hb[q * 4 + 1], h2 = hb[q * 4 + 2], h3 = hb[q * 4 + 3];
      float4 x;
      x = w0[q]; a0 += x.x * h0 + x.y * h1 + x.z * h2 + x.w * h3;
      x = w1[q]; a1 += x.x * h0 + x.y * h1 + x.z * h2 + x.w * h3;
      x = w2[q]; a2 += x.x * h0 + x.y * h1 + x.z * h2 + x.w * h3;
      x = w3[q]; a3 += x.x * h0 + x.y * h1 + x.z * h2 + x.w * h3;
    }
    a0 += __shfl_xor(a0, 32, 64);
    a1 += __shfl_xor(a1, 32, 64);
    a2 += __shfl_xor(a2, 32, 64);
    a3 += __shfl_xor(a3, 32, 64);
    if (lane < 32) {
      if (v + 0 < V_) out[(size_t)b * V_ + v + 0] = a0 + blm[v + 0];
      if (v + 1 < V_) out[(size_t)b * V_ + v + 1] = a1 + blm[v + 1];
      if (v + 2 < V_) out[(size_t)b * V_ + v + 2] = a2 + blm[v + 2];
      if (v + 3 < V_) out[(size_t)b * V_ + v + 3] = a3 + blm[v + 3];
    }
  }
}

extern "C" void kernel_launch(void* const* d_in, const int* in_sizes, int n_in,
                              void* d_out, int out_size, void* d_ws, size_t ws_size,
                              hipStream_t stream) {
  const int*   ids     = (const int*)d_in[0];
  const float* emb     = (const float*)d_in[1];
  const float* Wq      = (const float*)d_in[2];
  const float* Wk      = (const float*)d_in[3];
  const float* Wv      = (const float*)d_in[4];
  // d_in[5] = Wo (unused in forward)
  const float* Wg      = (const float*)d_in[6];
  const float* bg      = (const float*)d_in[7];
  const float* W_in    = (const float*)d_in[8];
  const float* b_in    = (const float*)d_in[9];
  const float* W_h     = (const float*)d_in[10];
  const float* log_tau = (const float*)d_in[11];
  const float* log_dt  = (const float*)d_in[12];
  const float* W_zx    = (const float*)d_in[13];
  const float* b_zx    = (const float*)d_in[14];
  const float* W_zh    = (const float*)d_in[15];
  const float* fast_W  = (const float*)d_in[16];
  const float* ln_g    = (const float*)d_in[17];
  const float* ln_b    = (const float*)d_in[18];
  const float* Wlm     = (const float*)d_in[19];
  const float* blm     = (const float*)d_in[20];

  char* ws = (char*)d_ws;
  float* x0    = (float*)(ws + OFF_X0);
  float* x1    = (float*)(ws + OFF_X1);
  float* xzb   = (float*)(ws + OFF_XZ);
  float* rbuf  = (float*)(ws + OFF_RBUF);
  float* ksum  = (float*)(ws + OFF_KSUM);
  float* kvsum = (float*)(ws + OFF_KVSUM);
  float* hA    = (float*)(ws + OFF_HA);
  float* hB    = (float*)(ws + OFF_HB);
  int*   bar   = (int*)(ws + OFF_BAR);
  float* hln   = (float*)(ws + OFF_HLN);
  float* out   = (float*)d_out;

  const int nzero = (int)ZERO_F4;
  zero_k<<<dim3((nzero + 255) / 256), dim3(256), 0, stream>>>((float4*)(ws + OFF_SMALL), nzero);
  embed_k<<<dim3(BT_ * 128 / 256), dim3(256), 0, stream>>>(ids, emb, x0);

  dim3 gg(BT_ / 64, 8);
  gemm_k<0><<<gg, dim3(256), 0, stream>>>(x0, Wk, Wv, nullptr, nullptr, nullptr, ksum, kvsum);
  gemm_k<1><<<gg, dim3(256), 0, stream>>>(x0, Wq, nullptr, nullptr, kvsum, ksum, rbuf, nullptr);
  gemm_k<2><<<gg, dim3(256), 0, stream>>>(x0, Wg, nullptr, bg, rbuf, x0, x1, nullptr);
  gemm_k<3><<<gg, dim3(256), 0, stream>>>(x1, W_in, nullptr, b_in, nullptr, nullptr, x0, nullptr);
  gemm_k<3><<<gg, dim3(256), 0, stream>>>(x1, W_zx, nullptr, b_zx, nullptr, nullptr, xzb, nullptr);

  scan_k<<<dim3(256), dim3(256), 0, stream>>>(x0, xzb, W_h, W_zh, fast_W, log_tau, log_dt, hA, hB, bar);

  pred_k<<<dim3(1), dim3(256), 0, stream>>>(hA, hB, out + (size_t)B_ * V_ + (size_t)B_ * H_);
  ln_k<<<dim3(32), dim3(256), 0, stream>>>(hA, ln_g, ln_b, hln, out + (size_t)B_ * V_);
  logits_k<<<dim3((V_ + 63) / 64), dim3(256), 0, stream>>>(hln, Wlm, blm, out);
}

// Round 2
// 13999.849 us; speedup vs baseline: 6.1817x; 6.1817x over previous
//
#include <hip/hip_runtime.h>
#include <cstdint>
#include <cstddef>

// MirrorLM forward, fp32 end-to-end.
//  B=32 T=2048 V=50257 D=H=512 NH=2 HD=256
// R2: scan sync rework — IF-coherent (sc0 sc1) h exchange, no threadfence,
// padded two-level barrier (16x16, 256B-spaced lines), register-carried h_old,
// xin/xz prefetch. GEMM/compute numerics unchanged from R1 (passed, absmax 0.0039).

#define B_ 32
#define T_ 2048
#define V_ 50257
#define D_ 512
#define H_ 512
#define NH_ 2
#define BT_ (B_*T_)   // 65536

typedef float f32x4 __attribute__((ext_vector_type(4)));

// ---- workspace layout (bytes). Requires ~404 MB of d_ws. ----
#define OFF_X0    ((size_t)0)                          // [BT][512] f32, later reused as xin
#define OFF_X1    (OFF_X0 + (size_t)BT_*D_*4)          // [BT][512] f32 (gated x)
#define OFF_XZ    (OFF_X1 + (size_t)BT_*D_*4)          // [BT][512] f32 (xz)
#define OFF_SMALL (OFF_XZ + (size_t)BT_*D_*4)
#define OFF_RBUF  (OFF_SMALL)                          // [BT][NH][2] f32 num/den = 1 MB
#define OFF_KSUM  (OFF_RBUF + (size_t)BT_*NH_*2*4)     // [B][512]
#define OFF_KVSUM (OFF_KSUM + (size_t)B_*D_*4)         // [B][512]
#define OFF_BAR   (OFF_KVSUM + (size_t)B_*D_*4)        // barrier, 12 KB padded lines
#define OFF_HA    (OFF_BAR + 12288)                    // h buffer A: [512][32] (j-major) — NOT pre-zeroed
#define OFF_HB    (OFF_HA + (size_t)H_*B_*4)           // h buffer B — NOT pre-zeroed
#define OFF_HLN   (OFF_HB + (size_t)H_*B_*4)           // LN'd h: [32][512]
#define ZERO_F4   ((OFF_HA - OFF_SMALL) / 16)          // zero RBUF..BAR only

__device__ __forceinline__ float phi_f(float x) {           // elu(x)+1
  return x > 0.f ? x + 1.f : expf(x);
}
__device__ __forceinline__ float sigm_f(float x) {
  return 1.f / (1.f + expf(-x));
}

// ---------------- zero small state ----------------
__global__ __launch_bounds__(256) void zero_k(float4* __restrict__ p, int n) {
  int i = blockIdx.x * 256 + threadIdx.x;
  if (i < n) p[i] = make_float4(0.f, 0.f, 0.f, 0.f);
}

// ---------------- embedding gather ----------------
__global__ __launch_bounds__(256) void embed_k(const int* __restrict__ ids,
                                               const float* __restrict__ emb,
                                               float* __restrict__ x0) {
  size_t idx = (size_t)blockIdx.x * 256 + threadIdx.x;   // over BT*128 float4
  int row = (int)(idx >> 7), c = (int)(idx & 127);
  int id = ids[row];
  ((float4*)x0)[idx] = ((const float4*)emb)[(size_t)id * 128 + c];
}

// ---------------- tiled fp32 GEMM, Y = X @ W^T, 64x64x32 tiles ----------------
// MODE 0: KV   -> phi(X@Wk^T), X@Wv^T; atomicAdd k_sum/kv_sum (reduce over t)
// MODE 1: Q    -> phi(X@Wq^T); atomicAdd num/den partials vs kv_sum/k_sum
// MODE 2: GATE -> gate=sigmoid(X@Wg^T+bg); x1 = gate*r + (1-gate)*x0
// MODE 3: LIN  -> X@W^T + bias
template<int MODE>
__global__ __launch_bounds__(256, 2) void gemm_k(
    const float* __restrict__ X, const float* __restrict__ W0,
    const float* __restrict__ W1, const float* __restrict__ bias,
    const float* __restrict__ aux0, const float* __restrict__ aux1,
    float* __restrict__ out0, float* __restrict__ out1) {
  constexpr bool KV = (MODE == 0);
  __shared__ float Xs[32][68];
  __shared__ float Ws[32][68];
  __shared__ float Ws2[KV ? 32 : 1][68];
  const int tid = threadIdx.x;
  const int m0 = blockIdx.x * 64, n0 = blockIdx.y * 64;
  const int tm = tid >> 4, tn = tid & 15;
  const int lr = tid >> 3;            // staging row 0..31
  const int lc = (tid & 7) * 4;       // staging k offset
  float acc[4][4] = {};
  float acc2[KV ? 4 : 1][4] = {};

  for (int k0 = 0; k0 < 512; k0 += 32) {
    const float4 xa = *(const float4*)&X[(size_t)(m0 + lr) * 512 + k0 + lc];
    const float4 xb = *(const float4*)&X[(size_t)(m0 + 32 + lr) * 512 + k0 + lc];
    const float4 wa = *(const float4*)&W0[(size_t)(n0 + lr) * 512 + k0 + lc];
    const float4 wb = *(const float4*)&W0[(size_t)(n0 + 32 + lr) * 512 + k0 + lc];
    float4 va, vb;
    if constexpr (KV) {
      va = *(const float4*)&W1[(size_t)(n0 + lr) * 512 + k0 + lc];
      vb = *(const float4*)&W1[(size_t)(n0 + 32 + lr) * 512 + k0 + lc];
    }
    __syncthreads();
    Xs[lc+0][lr] = xa.x; Xs[lc+1][lr] = xa.y; Xs[lc+2][lr] = xa.z; Xs[lc+3][lr] = xa.w;
    Xs[lc+0][lr+32] = xb.x; Xs[lc+1][lr+32] = xb.y; Xs[lc+2][lr+32] = xb.z; Xs[lc+3][lr+32] = xb.w;
    Ws[lc+0][lr] = wa.x; Ws[lc+1][lr] = wa.y; Ws[lc+2][lr] = wa.z; Ws[lc+3][lr] = wa.w;
    Ws[lc+0][lr+32] = wb.x; Ws[lc+1][lr+32] = wb.y; Ws[lc+2][lr+32] = wb.z; Ws[lc+3][lr+32] = wb.w;
    if constexpr (KV) {
      Ws2[lc+0][lr] = va.x; Ws2[lc+1][lr] = va.y; Ws2[lc+2][lr] = va.z; Ws2[lc+3][lr] = va.w;
      Ws2[lc+0][lr+32] = vb.x; Ws2[lc+1][lr+32] = vb.y; Ws2[lc+2][lr+32] = vb.z; Ws2[lc+3][lr+32] = vb.w;
    }
    __syncthreads();
    #pragma unroll
    for (int kk = 0; kk < 32; ++kk) {
      float4 xv = *(const float4*)&Xs[kk][tm * 4];
      float4 wv = *(const float4*)&Ws[kk][tn * 4];
      const float* xf = (const float*)&xv;
      const float* wf = (const float*)&wv;
      #pragma unroll
      for (int i = 0; i < 4; ++i)
        #pragma unroll
        for (int j = 0; j < 4; ++j)
          acc[i][j] += xf[i] * wf[j];
      if constexpr (KV) {
        float4 wv2 = *(const float4*)&Ws2[kk][tn * 4];
        const float* w2 = (const float*)&wv2;
        #pragma unroll
        for (int i = 0; i < 4; ++i)
          #pragma unroll
          for (int j = 0; j < 4; ++j)
            acc2[i][j] += xf[i] * w2[j];
      }
    }
  }

  if constexpr (MODE == 0) {          // KV epilogue: reduce over t (rows), atomic to k_sum/kv_sum
    __syncthreads();
    float* red = &Xs[0][0];           // 128 floats scratch
    if (tid < 128) red[tid] = 0.f;
    __syncthreads();
    #pragma unroll
    for (int j = 0; j < 4; ++j) {
      float ks = 0.f, kvs = 0.f;
      #pragma unroll
      for (int i = 0; i < 4; ++i) {
        float kk_ = phi_f(acc[i][j]);
        ks += kk_;
        kvs += kk_ * acc2[i][j];
      }
      atomicAdd(&red[(tn * 4 + j) * 2 + 0], ks);
      atomicAdd(&red[(tn * 4 + j) * 2 + 1], kvs);
    }
    __syncthreads();
    if (tid < 64) {
      int b = m0 >> 11;               // row block -> batch (2048 rows per batch)
      atomicAdd(&out0[b * 512 + n0 + tid], red[tid * 2 + 0]);
      atomicAdd(&out1[b * 512 + n0 + tid], red[tid * 2 + 1]);
    }
  } else if constexpr (MODE == 1) {   // Q epilogue: num/den partials
    int b = m0 >> 11;
    float kvv[4], ksv[4];
    #pragma unroll
    for (int j = 0; j < 4; ++j) {
      int n = n0 + tn * 4 + j;
      kvv[j] = aux0[b * 512 + n];
      ksv[j] = aux1[b * 512 + n];
    }
    __syncthreads();
    float* red = &Xs[0][0];
    if (tid < 128) red[tid] = 0.f;
    __syncthreads();
    #pragma unroll
    for (int i = 0; i < 4; ++i) {
      float np = 0.f, dp = 0.f;
      #pragma unroll
      for (int j = 0; j < 4; ++j) {
        float q = phi_f(acc[i][j]);
        np += q * kvv[j];
        dp += q * ksv[j];
      }
      atomicAdd(&red[(tm * 4 + i) * 2 + 0], np);
      atomicAdd(&red[(tm * 4 + i) * 2 + 1], dp);
    }
    __syncthreads();
    if (tid < 64) {
      int m = m0 + tid, h = n0 >> 8;
      atomicAdd(&out0[((size_t)m * 2 + h) * 2 + 0], red[tid * 2 + 0]);
      atomicAdd(&out0[((size_t)m * 2 + h) * 2 + 1], red[tid * 2 + 1]);
    }
  } else if constexpr (MODE == 2) {   // GATE epilogue: x1 = g*r + (1-g)*x0
    int h = n0 >> 8;
    #pragma unroll
    for (int i = 0; i < 4; ++i) {
      int m = m0 + tm * 4 + i;
      float rn = aux0[((size_t)m * 2 + h) * 2 + 0];
      float rd = aux0[((size_t)m * 2 + h) * 2 + 1];
      float r = rn / (rd + 1e-6f);
      float4 x0v = *(const float4*)&aux1[(size_t)m * 512 + n0 + tn * 4];
      const float* xf = (const float*)&x0v;
      float4 o;
      float* of = (float*)&o;
      #pragma unroll
      for (int j = 0; j < 4; ++j) {
        int n = n0 + tn * 4 + j;
        float g = sigm_f(acc[i][j] + bias[n]);
        of[j] = g * r + (1.f - g) * xf[j];
      }
      *(float4*)&out0[(size_t)m * 512 + n0 + tn * 4] = o;
    }
  } else {                            // LIN epilogue
    #pragma unroll
    for (int i = 0; i < 4; ++i) {
      int m = m0 + tm * 4 + i;
      float4 o;
      float* of = (float*)&o;
      #pragma unroll
      for (int j = 0; j < 4; ++j)
        of[j] = acc[i][j] + bias[n0 + tn * 4 + j];
      *(float4*)&out0[(size_t)m * 512 + n0 + tn * 4] = o;
    }
  }
}

// ---------------- persistent GRU scan ----------------
// 256 WGs x 256 threads. WG bid owns h-columns j0=2*bid, j0+1 of W_h, W_zh, fast_W (LDS).
// h buffers [512][32] j-major, exchanged via IF-coherent sc0/sc1 vector ops.
// Barrier: 16 leaves x 16 WGs, every counter/release word on its own 256-B line.
__global__ __launch_bounds__(256) void scan_k(
    const float* __restrict__ xin, const float* __restrict__ xz,
    const float* __restrict__ Wh, const float* __restrict__ Wzh,
    const float* __restrict__ fastW,
    const float* __restrict__ log_tau, const float* __restrict__ log_dt,
    float* __restrict__ hA, float* __restrict__ hB,
    int* __restrict__ bar) {
  __shared__ float w_lds[6][512];   // 0:Wh j0 1:Wh j1 2:Wzh j0 3:Wzh j1 4:fw j0 5:fw j1
  __shared__ float red[768];
  __shared__ float sums[192];
  __shared__ float s_misc[4];       // dt0 dt1 tau0 tau1
  const int tid = threadIdx.x, bid = blockIdx.x;
  const int j0 = bid * 2;
  for (int idx = tid; idx < 2048; idx += 256) {
    int r = idx >> 9, c = idx & 511;
    const float* src = (r < 2) ? Wh : Wzh;
    w_lds[r][c] = src[(size_t)(j0 + (r & 1)) * 512 + c];
  }
  for (int idx = tid; idx < 1024; idx += 256) {
    int r = idx >> 9, c = idx & 511;
    w_lds[4 + r][c] = fastW[(size_t)c * 512 + (j0 + r)];
  }
  if (tid < 2) {
    s_misc[tid] = expf(log_dt[j0 + tid]);
    s_misc[2 + tid] = expf(log_tau[j0 + tid]);
  }
  __syncthreads();
  const int lane = tid & 63, wid = tid >> 6;
  const int bq = lane & 7;                      // b-quad (4 batches)
  const int i0 = (wid * 8 + (lane >> 3)) * 16;  // this thread's k-range start
  const int jj = tid >> 5, bb = tid & 31;       // for tid<64 epilogue
  const int g = bid >> 4;                       // leaf group
  int* leafc = bar + g * 64;                    // 256-B spaced
  int* rootc = bar + 1024;
  int* relw  = bar + 2048 + g * 64;

  float hold = 0.f;                             // h_old carried in-register (this WG owns (jj,bb))
  float nxin = 0.f, nxz = 0.f;
  if (tid < 64) {
    size_t off = ((size_t)bb * T_) * 512 + (j0 + jj);
    nxin = xin[off];
    nxz = xz[off];
  }

  for (int t = 0; t < 2048; ++t) {
    const float* hc = (t & 1) ? hB : hA;
    float* hn = (t & 1) ? hA : hB;
    float pxin = nxin, pxz = nxz;
    if (tid < 64 && t + 1 < T_) {               // prefetch next step's xin/xz
      size_t off = ((size_t)bb * T_ + (t + 1)) * 512 + (j0 + jj);
      nxin = xin[off];
      nxz = xz[off];
    }
    f32x4 hv[16];
    if (t != 0) {
      const f32x4* hb4 = (const f32x4*)hc + (size_t)i0 * 8 + bq;
      // IF-coherent loads (bypass L1/L2): 16x global_load_dwordx4 sc0 sc1
      #define HL(r, byteoff) asm volatile("global_load_dwordx4 %0, %1, off offset:" #byteoff " sc0 sc1" \
                                          : "=v"(hv[r]) : "v"(hb4))
      HL(0, 0);    HL(1, 128);  HL(2, 256);  HL(3, 384);
      HL(4, 512);  HL(5, 640);  HL(6, 768);  HL(7, 896);
      HL(8, 1024); HL(9, 1152); HL(10, 1280); HL(11, 1408);
      HL(12, 1536); HL(13, 1664); HL(14, 1792); HL(15, 1920);
      #undef HL
      asm volatile("s_waitcnt vmcnt(0)" ::: "memory");
    } else {
      #pragma unroll
      for (int r = 0; r < 16; ++r) hv[r] = (f32x4){0.f, 0.f, 0.f, 0.f};
    }

    float a[6][4];
    #pragma unroll
    for (int p = 0; p < 6; ++p) { a[p][0] = 0.f; a[p][1] = 0.f; a[p][2] = 0.f; a[p][3] = 0.f; }
    #pragma unroll
    for (int blk = 0; blk < 4; ++blk) {
      const float* h0 = (const float*)&hv[blk * 4 + 0];
      const float* h1 = (const float*)&hv[blk * 4 + 1];
      const float* h2 = (const float*)&hv[blk * 4 + 2];
      const float* h3 = (const float*)&hv[blk * 4 + 3];
      #pragma unroll
      for (int p = 0; p < 6; ++p) {
        float4 wp4 = *(const float4*)&w_lds[p][i0 + blk * 4];
        const float* wp = (const float*)&wp4;
        #pragma unroll
        for (int q = 0; q < 4; ++q)
          a[p][q] += wp[0] * h0[q] + wp[1] * h1[q] + wp[2] * h2[q] + wp[3] * h3[q];
      }
    }
    // reduce over k-segments: within wave (lane bits 3..5), then across 4 waves via LDS
    #pragma unroll
    for (int m = 8; m <= 32; m <<= 1)
      #pragma unroll
      for (int p = 0; p < 6; ++p)
        #pragma unroll
        for (int q = 0; q < 4; ++q)
          a[p][q] += __shfl_xor(a[p][q], m, 64);
    if ((lane >> 3) == 0) {
      #pragma unroll
      for (int p = 0; p < 6; ++p)
        #pragma unroll
        for (int q = 0; q < 4; ++q)
          red[((wid * 8 + lane) * 6 + p) * 4 + q] = a[p][q];
    }
    __syncthreads();
    if (tid < 192) {
      int p = tid >> 5, b = tid & 31;
      float s = 0.f;
      #pragma unroll
      for (int w = 0; w < 4; ++w) s += red[((w * 8 + (b >> 2)) * 6 + p) * 4 + (b & 3)];
      sums[p * 32 + b] = s;
    }
    __syncthreads();
    if (tid < 64) {
      float u = pxin + sums[jj * 32 + bb];
      float f = tanhf(u);
      float dtv = s_misc[jj], tauv = s_misc[2 + jj];
      float hl = hold + dtv * (f - tauv * hold);
      float zv = sigm_f(pxz + sums[(2 + jj) * 32 + bb]);
      float slow = (1.f - zv) * hold + zv * hl;
      float hnval = slow + sums[(4 + jj) * 32 + bb];
      hold = hnval;
      float* dst = hn + (j0 + jj) * 32 + bb;
      asm volatile("global_store_dword %0, %1, off sc0 sc1" :: "v"(dst), "v"(hnval) : "memory");
    }
    asm volatile("s_waitcnt vmcnt(0)" ::: "memory");   // h-slice visible at IF before arrival
    // ---- two-level padded barrier, monotonic counters ----
    if (tid == 0) {
      int old = __hip_atomic_fetch_add(leafc, 1, __ATOMIC_RELAXED, __HIP_MEMORY_SCOPE_AGENT);
      if (old == 16 * (t + 1) - 1) {
        int r = __hip_atomic_fetch_add(rootc, 1, __ATOMIC_RELAXED, __HIP_MEMORY_SCOPE_AGENT);
        if (r == 16 * (t + 1) - 1) {
          #pragma unroll
          for (int i = 0; i < 16; ++i)
            __hip_atomic_store(bar + 2048 + i * 64, t + 1, __ATOMIC_RELAXED, __HIP_MEMORY_SCOPE_AGENT);
        }
      }
      while (__hip_atomic_load(relw, __ATOMIC_RELAXED, __HIP_MEMORY_SCOPE_AGENT) < t + 1)
        __builtin_amdgcn_s_sleep(4);
    }
    __syncthreads();
  }
}

// ---------------- pred_error_norm ----------------
__global__ __launch_bounds__(256) void pred_k(const float* __restrict__ hA,
                                              const float* __restrict__ hB,
                                              float* __restrict__ out) {
  const int tid = threadIdx.x;
  float s = 0.f;
  for (int i = tid; i < H_ * B_; i += 256) {
    float a = __hip_atomic_load((const float*)&hA[i], __ATOMIC_RELAXED, __HIP_MEMORY_SCOPE_AGENT);
    float b = __hip_atomic_load((const float*)&hB[i], __ATOMIC_RELAXED, __HIP_MEMORY_SCOPE_AGENT);
    float d = a - b;
    s += d * d;
  }
  #pragma unroll
  for (int m = 1; m < 64; m <<= 1) s += __shfl_xor(s, m, 64);
  __shared__ float r8[4];
  if ((tid & 63) == 0) r8[tid >> 6] = s;
  __syncthreads();
  if (tid == 0) out[0] = sqrtf((r8[0] + r8[1] + r8[2] + r8[3]) * (1.f / (H_ * B_)));
}

// ---------------- LayerNorm over h_last ----------------
__global__ __launch_bounds__(256) void ln_k(const float* __restrict__ hA,   // [512][32]
                                            const float* __restrict__ g,
                                            const float* __restrict__ be,
                                            float* __restrict__ hln,        // [32][512]
                                            float* __restrict__ outh) {
  const int b = blockIdx.x, tid = threadIdx.x;
  float v0 = __hip_atomic_load((const float*)&hA[tid * 32 + b], __ATOMIC_RELAXED, __HIP_MEMORY_SCOPE_AGENT);
  float v1 = __hip_atomic_load((const float*)&hA[(tid + 256) * 32 + b], __ATOMIC_RELAXED, __HIP_MEMORY_SCOPE_AGENT);
  float s = v0 + v1;
  #pragma unroll
  for (int m = 1; m < 64; m <<= 1) s += __shfl_xor(s, m, 64);
  __shared__ float r8[8];
  if ((tid & 63) == 0) r8[tid >> 6] = s;
  __syncthreads();
  float mu = (r8[0] + r8[1] + r8[2] + r8[3]) * (1.f / 512.f);
  float d0 = v0 - mu, d1 = v1 - mu;
  float s2 = d0 * d0 + d1 * d1;
  #pragma unroll
  for (int m = 1; m < 64; m <<= 1) s2 += __shfl_xor(s2, m, 64);
  if ((tid & 63) == 0) r8[4 + (tid >> 6)] = s2;
  __syncthreads();
  float var = (r8[4] + r8[5] + r8[6] + r8[7]) * (1.f / 512.f);
  float inv = rsqrtf(var + 1e-5f);
  float y0 = d0 * inv * g[tid] + be[tid];
  float y1 = d1 * inv * g[tid + 256] + be[tid + 256];
  hln[b * 512 + tid] = y0;
  hln[b * 512 + tid + 256] = y1;
  outh[b * 512 + tid] = y0;
  outh[b * 512 + tid + 256] = y1;
}

// ---------------- LM head: logits = hln @ Wlm^T + blm ----------------
__global__ __launch_bounds__(256, 2) void logits_k(const float* __restrict__ hln,
                                                   const float* __restrict__ Wlm,
                                                   const float* __restrict__ blm,
                                                   float* __restrict__ out) {
  __shared__ float hs[32 * 513];
  const int tid = threadIdx.x;
  for (int idx = tid; idx < 16384; idx += 256) {
    int b = idx >> 9, k = idx & 511;
    hs[b * 513 + k] = hln[idx];
  }
  __syncthreads();
  const int lane = tid & 63, w = tid >> 6;
  const int b = lane & 31, kh = lane >> 5;
  const float* hb = &hs[b * 513 + kh * 256];
  const int vbase = blockIdx.x * 64 + w * 16;
  for (int r4 = 0; r4 < 16; r4 += 4) {
    int v = vbase + r4;
    int v0i = (v + 0 < V_) ? v + 0 : V_ - 1;
    int v1i = (v + 1 < V_) ? v + 1 : V_ - 1;
    int v2i = (v + 2 < V_) ? v + 2 : V_ - 1;
    int v3i = (v + 3 < V_) ? v + 3 : V_ - 1;
    const float4* w0 = (const float4*)&Wlm[(size_t)v0i * 512 + kh * 256];
    const float4* w1 = (const float4*)&Wlm[(size_t)v1i * 512 + kh * 256];
    const float4* w2 = (const float4*)&Wlm[(size_t)v2i * 512 + kh * 256];
    const float4* w3 = (const float4*)&Wlm[(size_t)v3i * 512 + kh * 256];
    float a0 = 0.f, a1 = 0.f, a2 = 0.f, a3 = 0.f;
    #pragma unroll 8
    for (int q = 0; q < 64; ++q) {
      float h0 = hb[q * 4 + 0], h1 = hb[q * 4 + 1], h2 = hb[q * 4 + 2], h3 = hb[q * 4 + 3];
      float4 x;
      x = w0[q]; a0 += x.x * h0 + x.y * h1 + x.z * h2 + x.w * h3;
      x = w1[q]; a1 += x.x * h0 + x.y * h1 + x.z * h2 + x.w * h3;
      x = w2[q]; a2 += x.x * h0 + x.y * h1 + x.z * h2 + x.w * h3;
      x = w3[q]; a3 += x.x * h0 + x.y * h1 + x.z * h2 + x.w * h3;
    }
    a0 += __shfl_xor(a0, 32, 64);
    a1 += __shfl_xor(a1, 32, 64);
    a2 += __shfl_xor(a2, 32, 64);
    a3 += __shfl_xor(a3, 32, 64);
    if (lane < 32) {
      if (v + 0 < V_) out[(size_t)b * V_ + v + 0] = a0 + blm[v + 0];
      if (v + 1 < V_) out[(size_t)b * V_ + v + 1] = a1 + blm[v + 1];
      if (v + 2 < V_) out[(size_t)b * V_ + v + 2] = a2 + blm[v + 2];
      if (v + 3 < V_) out[(size_t)b * V_ + v + 3] = a3 + blm[v + 3];
    }
  }
}

extern "C" void kernel_launch(void* const* d_in, const int* in_sizes, int n_in,
                              void* d_out, int out_size, void* d_ws, size_t ws_size,
                              hipStream_t stream) {
  const int*   ids     = (const int*)d_in[0];
  const float* emb     = (const float*)d_in[1];
  const float* Wq      = (const float*)d_in[2];
  const float* Wk      = (const float*)d_in[3];
  const float* Wv      = (const float*)d_in[4];
  // d_in[5] = Wo (unused in forward)
  const float* Wg      = (const float*)d_in[6];
  const float* bg      = (const float*)d_in[7];
  const float* W_in    = (const float*)d_in[8];
  const float* b_in    = (const float*)d_in[9];
  const float* W_h     = (const float*)d_in[10];
  const float* log_tau = (const float*)d_in[11];
  const float* log_dt  = (const float*)d_in[12];
  const float* W_zx    = (const float*)d_in[13];
  const float* b_zx    = (const float*)d_in[14];
  const float* W_zh    = (const float*)d_in[15];
  const float* fast_W  = (const float*)d_in[16];
  const float* ln_g    = (const float*)d_in[17];
  const float* ln_b    = (const float*)d_in[18];
  const float* Wlm     = (const float*)d_in[19];
  const float* blm     = (const float*)d_in[20];

  char* ws = (char*)d_ws;
  float* x0    = (float*)(ws + OFF_X0);
  float* x1    = (float*)(ws + OFF_X1);
  float* xzb   = (float*)(ws + OFF_XZ);
  float* rbuf  = (float*)(ws + OFF_RBUF);
  float* ksum  = (float*)(ws + OFF_KSUM);
  float* kvsum = (float*)(ws + OFF_KVSUM);
  int*   bar   = (int*)(ws + OFF_BAR);
  float* hA    = (float*)(ws + OFF_HA);
  float* hB    = (float*)(ws + OFF_HB);
  float* hln   = (float*)(ws + OFF_HLN);
  float* out   = (float*)d_out;

  const int nzero = (int)ZERO_F4;
  zero_k<<<dim3((nzero + 255) / 256), dim3(256), 0, stream>>>((float4*)(ws + OFF_SMALL), nzero);
  embed_k<<<dim3(BT_ * 128 / 256), dim3(256), 0, stream>>>(ids, emb, x0);

  dim3 gg(BT_ / 64, 8);
  gemm_k<0><<<gg, dim3(256), 0, stream>>>(x0, Wk, Wv, nullptr, nullptr, nullptr, ksum, kvsum);
  gemm_k<1><<<gg, dim3(256), 0, stream>>>(x0, Wq, nullptr, nullptr, kvsum, ksum, rbuf, nullptr);
  gemm_k<2><<<gg, dim3(256), 0, stream>>>(x0, Wg, nullptr, bg, rbuf, x0, x1, nullptr);
  gemm_k<3><<<gg, dim3(256), 0, stream>>>(x1, W_in, nullptr, b_in, nullptr, nullptr, x0, nullptr);
  gemm_k<3><<<gg, dim3(256), 0, stream>>>(x1, W_zx, nullptr, b_zx, nullptr, nullptr, xzb, nullptr);

  scan_k<<<dim3(256), dim3(256), 0, stream>>>(x0, xzb, W_h, W_zh, fast_W, log_tau, log_dt, hA, hB, bar);

  pred_k<<<dim3(1), dim3(256), 0, stream>>>(hA, hB, out + (size_t)B_ * V_ + (size_t)B_ * H_);
  ln_k<<<dim3(32), dim3(256), 0, stream>>>(hA, ln_g, ln_b, hln, out + (size_t)B_ * V_);
  logits_k<<<dim3((V_ + 63) / 64), dim3(256), 0, stream>>>(hln, Wlm, blm, out);
}

// Round 3
// 12158.675 us; speedup vs baseline: 7.1178x; 1.1514x over previous
//
#include <hip/hip_runtime.h>
#include <cstdint>
#include <cstddef>

// MirrorLM forward, fp32 end-to-end.
//  B=32 T=2048 V=50257 D=H=512 NH=2 HD=256
// R3: scan repartitioned to (batch-group=4, j-chunk=16) per WG:
//  - sync = per-WG flag stores + polling (no atomic RMW at all)
//  - weights in VGPRs (no LDS weight stream, no bank conflicts)
//  - IF h-broadcast 16 MB/step -> 2 MB/step
// GEMM phase unchanged from R2 (passed, absmax 0.0039).

#define B_ 32
#define T_ 2048
#define V_ 50257
#define D_ 512
#define H_ 512
#define NH_ 2
#define BT_ (B_*T_)   // 65536

typedef float f32x4 __attribute__((ext_vector_type(4)));

// ---- workspace layout (bytes). Requires ~404 MB of d_ws. ----
#define OFF_X0    ((size_t)0)                          // [BT][512] f32, later reused as xin
#define OFF_X1    (OFF_X0 + (size_t)BT_*D_*4)          // [BT][512] f32 (gated x)
#define OFF_XZ    (OFF_X1 + (size_t)BT_*D_*4)          // [BT][512] f32 (xz)
#define OFF_SMALL (OFF_XZ + (size_t)BT_*D_*4)
#define OFF_RBUF  (OFF_SMALL)                          // [BT][NH][2] f32 num/den = 1 MB
#define OFF_KSUM  (OFF_RBUF + (size_t)BT_*NH_*2*4)     // [B][512]
#define OFF_KVSUM (OFF_KSUM + (size_t)B_*D_*4)         // [B][512]
#define OFF_FLAGS (OFF_KVSUM + (size_t)B_*D_*4)        // 256 flags x 64 B = 16 KB
#define OFF_HBUF  (OFF_FLAGS + 16384)                  // [2][32][512] f32 — NOT pre-zeroed
#define OFF_HLN   (OFF_HBUF + (size_t)2*B_*H_*4)       // LN'd h: [32][512]
#define ZERO_F4   ((OFF_HBUF - OFF_SMALL) / 16)        // zero RBUF..FLAGS

__device__ __forceinline__ float phi_f(float x) {           // elu(x)+1
  return x > 0.f ? x + 1.f : expf(x);
}
__device__ __forceinline__ float sigm_f(float x) {
  return 1.f / (1.f + expf(-x));
}

// ---------------- zero small state ----------------
__global__ __launch_bounds__(256) void zero_k(float4* __restrict__ p, int n) {
  int i = blockIdx.x * 256 + threadIdx.x;
  if (i < n) p[i] = make_float4(0.f, 0.f, 0.f, 0.f);
}

// ---------------- embedding gather ----------------
__global__ __launch_bounds__(256) void embed_k(const int* __restrict__ ids,
                                               const float* __restrict__ emb,
                                               float* __restrict__ x0) {
  size_t idx = (size_t)blockIdx.x * 256 + threadIdx.x;   // over BT*128 float4
  int row = (int)(idx >> 7), c = (int)(idx & 127);
  int id = ids[row];
  ((float4*)x0)[idx] = ((const float4*)emb)[(size_t)id * 128 + c];
}

// ---------------- tiled fp32 GEMM, Y = X @ W^T, 64x64x32 tiles ----------------
// MODE 0: KV   -> phi(X@Wk^T), X@Wv^T; atomicAdd k_sum/kv_sum (reduce over t)
// MODE 1: Q    -> phi(X@Wq^T); atomicAdd num/den partials vs kv_sum/k_sum
// MODE 2: GATE -> gate=sigmoid(X@Wg^T+bg); x1 = gate*r + (1-gate)*x0
// MODE 3: LIN  -> X@W^T + bias
template<int MODE>
__global__ __launch_bounds__(256, 2) void gemm_k(
    const float* __restrict__ X, const float* __restrict__ W0,
    const float* __restrict__ W1, const float* __restrict__ bias,
    const float* __restrict__ aux0, const float* __restrict__ aux1,
    float* __restrict__ out0, float* __restrict__ out1) {
  constexpr bool KV = (MODE == 0);
  __shared__ float Xs[32][68];
  __shared__ float Ws[32][68];
  __shared__ float Ws2[KV ? 32 : 1][68];
  const int tid = threadIdx.x;
  const int m0 = blockIdx.x * 64, n0 = blockIdx.y * 64;
  const int tm = tid >> 4, tn = tid & 15;
  const int lr = tid >> 3;            // staging row 0..31
  const int lc = (tid & 7) * 4;       // staging k offset
  float acc[4][4] = {};
  float acc2[KV ? 4 : 1][4] = {};

  for (int k0 = 0; k0 < 512; k0 += 32) {
    const float4 xa = *(const float4*)&X[(size_t)(m0 + lr) * 512 + k0 + lc];
    const float4 xb = *(const float4*)&X[(size_t)(m0 + 32 + lr) * 512 + k0 + lc];
    const float4 wa = *(const float4*)&W0[(size_t)(n0 + lr) * 512 + k0 + lc];
    const float4 wb = *(const float4*)&W0[(size_t)(n0 + 32 + lr) * 512 + k0 + lc];
    float4 va, vb;
    if constexpr (KV) {
      va = *(const float4*)&W1[(size_t)(n0 + lr) * 512 + k0 + lc];
      vb = *(const float4*)&W1[(size_t)(n0 + 32 + lr) * 512 + k0 + lc];
    }
    __syncthreads();
    Xs[lc+0][lr] = xa.x; Xs[lc+1][lr] = xa.y; Xs[lc+2][lr] = xa.z; Xs[lc+3][lr] = xa.w;
    Xs[lc+0][lr+32] = xb.x; Xs[lc+1][lr+32] = xb.y; Xs[lc+2][lr+32] = xb.z; Xs[lc+3][lr+32] = xb.w;
    Ws[lc+0][lr] = wa.x; Ws[lc+1][lr] = wa.y; Ws[lc+2][lr] = wa.z; Ws[lc+3][lr] = wa.w;
    Ws[lc+0][lr+32] = wb.x; Ws[lc+1][lr+32] = wb.y; Ws[lc+2][lr+32] = wb.z; Ws[lc+3][lr+32] = wb.w;
    if constexpr (KV) {
      Ws2[lc+0][lr] = va.x; Ws2[lc+1][lr] = va.y; Ws2[lc+2][lr] = va.z; Ws2[lc+3][lr] = va.w;
      Ws2[lc+0][lr+32] = vb.x; Ws2[lc+1][lr+32] = vb.y; Ws2[lc+2][lr+32] = vb.z; Ws2[lc+3][lr+32] = vb.w;
    }
    __syncthreads();
    #pragma unroll
    for (int kk = 0; kk < 32; ++kk) {
      float4 xv = *(const float4*)&Xs[kk][tm * 4];
      float4 wv = *(const float4*)&Ws[kk][tn * 4];
      const float* xf = (const float*)&xv;
      const float* wf = (const float*)&wv;
      #pragma unroll
      for (int i = 0; i < 4; ++i)
        #pragma unroll
        for (int j = 0; j < 4; ++j)
          acc[i][j] += xf[i] * wf[j];
      if constexpr (KV) {
        float4 wv2 = *(const float4*)&Ws2[kk][tn * 4];
        const float* w2 = (const float*)&wv2;
        #pragma unroll
        for (int i = 0; i < 4; ++i)
          #pragma unroll
          for (int j = 0; j < 4; ++j)
            acc2[i][j] += xf[i] * w2[j];
      }
    }
  }

  if constexpr (MODE == 0) {          // KV epilogue: reduce over t (rows), atomic to k_sum/kv_sum
    __syncthreads();
    float* red = &Xs[0][0];           // 128 floats scratch
    if (tid < 128) red[tid] = 0.f;
    __syncthreads();
    #pragma unroll
    for (int j = 0; j < 4; ++j) {
      float ks = 0.f, kvs = 0.f;
      #pragma unroll
      for (int i = 0; i < 4; ++i) {
        float kk_ = phi_f(acc[i][j]);
        ks += kk_;
        kvs += kk_ * acc2[i][j];
      }
      atomicAdd(&red[(tn * 4 + j) * 2 + 0], ks);
      atomicAdd(&red[(tn * 4 + j) * 2 + 1], kvs);
    }
    __syncthreads();
    if (tid < 64) {
      int b = m0 >> 11;               // row block -> batch (2048 rows per batch)
      atomicAdd(&out0[b * 512 + n0 + tid], red[tid * 2 + 0]);
      atomicAdd(&out1[b * 512 + n0 + tid], red[tid * 2 + 1]);
    }
  } else if constexpr (MODE == 1) {   // Q epilogue: num/den partials
    int b = m0 >> 11;
    float kvv[4], ksv[4];
    #pragma unroll
    for (int j = 0; j < 4; ++j) {
      int n = n0 + tn * 4 + j;
      kvv[j] = aux0[b * 512 + n];
      ksv[j] = aux1[b * 512 + n];
    }
    __syncthreads();
    float* red = &Xs[0][0];
    if (tid < 128) red[tid] = 0.f;
    __syncthreads();
    #pragma unroll
    for (int i = 0; i < 4; ++i) {
      float np = 0.f, dp = 0.f;
      #pragma unroll
      for (int j = 0; j < 4; ++j) {
        float q = phi_f(acc[i][j]);
        np += q * kvv[j];
        dp += q * ksv[j];
      }
      atomicAdd(&red[(tm * 4 + i) * 2 + 0], np);
      atomicAdd(&red[(tm * 4 + i) * 2 + 1], dp);
    }
    __syncthreads();
    if (tid < 64) {
      int m = m0 + tid, h = n0 >> 8;
      atomicAdd(&out0[((size_t)m * 2 + h) * 2 + 0], red[tid * 2 + 0]);
      atomicAdd(&out0[((size_t)m * 2 + h) * 2 + 1], red[tid * 2 + 1]);
    }
  } else if constexpr (MODE == 2) {   // GATE epilogue: x1 = g*r + (1-g)*x0
    int h = n0 >> 8;
    #pragma unroll
    for (int i = 0; i < 4; ++i) {
      int m = m0 + tm * 4 + i;
      float rn = aux0[((size_t)m * 2 + h) * 2 + 0];
      float rd = aux0[((size_t)m * 2 + h) * 2 + 1];
      float r = rn / (rd + 1e-6f);
      float4 x0v = *(const float4*)&aux1[(size_t)m * 512 + n0 + tn * 4];
      const float* xf = (const float*)&x0v;
      float4 o;
      float* of = (float*)&o;
      #pragma unroll
      for (int j = 0; j < 4; ++j) {
        int n = n0 + tn * 4 + j;
        float g = sigm_f(acc[i][j] + bias[n]);
        of[j] = g * r + (1.f - g) * xf[j];
      }
      *(float4*)&out0[(size_t)m * 512 + n0 + tn * 4] = o;
    }
  } else {                            // LIN epilogue
    #pragma unroll
    for (int i = 0; i < 4; ++i) {
      int m = m0 + tm * 4 + i;
      float4 o;
      float* of = (float*)&o;
      #pragma unroll
      for (int j = 0; j < 4; ++j)
        of[j] = acc[i][j] + bias[n0 + tn * 4 + j];
      *(float4*)&out0[(size_t)m * 512 + n0 + tn * 4] = o;
    }
  }
}

// ---------------- persistent GRU scan ----------------
// 256 WGs x 256 threads. WG (g = bid>>5, c = bid&31) owns batches g*4..g*4+3,
// j-columns c*16..c*16+15. Thread (j = tid&15, ks = tid>>4) holds weights
// W_h/W_zh rows jg, fast_W col jg, k-slice [ks*32, ks*32+32) in VGPRs.
// h: [2][32][512] global, exchanged IF-coherent (sc0 sc1). Sync: per-WG flag
// stores on private 64-B lines; consumers poll the 32 flags of their group.
__global__ __launch_bounds__(256, 1) void scan_k(
    const float* __restrict__ xin, const float* __restrict__ xz,
    const float* __restrict__ Wh, const float* __restrict__ Wzh,
    const float* __restrict__ fastW,
    const float* __restrict__ log_tau, const float* __restrict__ log_dt,
    float* __restrict__ hbuf, int* __restrict__ flags) {
  __shared__ float red[2][4][16][12];   // [parity][wave][j][m*4+b]
  const int tid = threadIdx.x;
  const int c = blockIdx.x & 31;        // j-chunk
  const int g = blockIdx.x >> 5;        // batch group
  const int lane = tid & 63, w = tid >> 6;
  const int j = tid & 15, ks = tid >> 4;
  const int jg = c * 16 + j;
  const int kb = ks * 32;

  // ---- weights into VGPRs (one-time) ----
  f32x4 wh[8], wz[8], fw[8];
  #pragma unroll
  for (int i = 0; i < 8; ++i) {
    wh[i] = *(const f32x4*)&Wh[(size_t)jg * 512 + kb + i * 4];
    wz[i] = *(const f32x4*)&Wzh[(size_t)jg * 512 + kb + i * 4];
    f32x4 t;
    t.x = fastW[(size_t)(kb + i * 4 + 0) * 512 + jg];
    t.y = fastW[(size_t)(kb + i * 4 + 1) * 512 + jg];
    t.z = fastW[(size_t)(kb + i * 4 + 2) * 512 + jg];
    t.w = fastW[(size_t)(kb + i * 4 + 3) * 512 + jg];
    fw[i] = t;
  }
  // epilogue constants (wave 0: lane = eb*16 + ej)
  const int eb = lane >> 4, ej = lane & 15;
  const int ejg = c * 16 + ej;
  const int bglob = g * 4 + eb;
  const float dtv = expf(log_dt[ejg]);
  const float tauv = expf(log_tau[ejg]);
  float hold = 0.f;
  int* grpflags = flags + g * 32 * 16;  // 32 flags, 64-B spaced
  asm volatile("s_waitcnt vmcnt(0)" ::: "memory");   // weights resident

  for (int t = 0; t < 2048; ++t) {
    const float* hc = hbuf + (size_t)(t & 1) * (B_ * H_);
    float* hn = hbuf + (size_t)((t + 1) & 1) * (B_ * H_);
    // ---- wait for h_t (all 32 chunks of this group) ----
    if (t != 0) {
      int* fl = grpflags + (lane & 31) * 16;
      while (true) {
        int v = __hip_atomic_load(fl, __ATOMIC_RELAXED, __HIP_MEMORY_SCOPE_AGENT);
        unsigned long long m = __ballot((lane < 32) ? (v >= t) : 1);
        if (m == ~0ull) break;
        __builtin_amdgcn_s_sleep(1);
      }
    }
    // ---- xin/xz for this step (wave 0 only; folded into asm vmcnt discipline) ----
    float pxin, pxz;
    if (w == 0) {
      size_t xo = ((size_t)bglob * T_ + t) * 512 + ejg;
      const float* xip = xin + xo;
      const float* xzp = xz + xo;
      asm volatile("global_load_dword %0, %2, off\n\t"
                   "global_load_dword %1, %3, off"
                   : "=v"(pxin), "=v"(pxz) : "v"(xip), "v"(xzp));
    }
    // ---- load h_t slices (IF-coherent), MAC ----
    float am[3][4];
    #pragma unroll
    for (int m = 0; m < 3; ++m)
      #pragma unroll
      for (int b = 0; b < 4; ++b) am[m][b] = 0.f;
    if (t != 0) {
      f32x4 hv[4][8];
      #pragma unroll
      for (int b = 0; b < 4; ++b) {
        const float* hp = hc + ((g * 4 + b) * 512 + kb);
        asm volatile(
          "global_load_dwordx4 %0, %8, off sc0 sc1\n\t"
          "global_load_dwordx4 %1, %8, off offset:16 sc0 sc1\n\t"
          "global_load_dwordx4 %2, %8, off offset:32 sc0 sc1\n\t"
          "global_load_dwordx4 %3, %8, off offset:48 sc0 sc1\n\t"
          "global_load_dwordx4 %4, %8, off offset:64 sc0 sc1\n\t"
          "global_load_dwordx4 %5, %8, off offset:80 sc0 sc1\n\t"
          "global_load_dwordx4 %6, %8, off offset:96 sc0 sc1\n\t"
          "global_load_dwordx4 %7, %8, off offset:112 sc0 sc1"
          : "=v"(hv[b][0]), "=v"(hv[b][1]), "=v"(hv[b][2]), "=v"(hv[b][3]),
            "=v"(hv[b][4]), "=v"(hv[b][5]), "=v"(hv[b][6]), "=v"(hv[b][7])
          : "v"(hp));
      }
      #pragma unroll
      for (int b = 0; b < 4; ++b) {
        // stage waits: oldest 8*(b+1) h-loads done (+2 xin loads on wave 0)
        if (b == 0) asm volatile("s_waitcnt vmcnt(24)"
          : "+v"(hv[0][0]), "+v"(hv[0][1]), "+v"(hv[0][2]), "+v"(hv[0][3]),
            "+v"(hv[0][4]), "+v"(hv[0][5]), "+v"(hv[0][6]), "+v"(hv[0][7]));
        else if (b == 1) asm volatile("s_waitcnt vmcnt(16)"
          : "+v"(hv[1][0]), "+v"(hv[1][1]), "+v"(hv[1][2]), "+v"(hv[1][3]),
            "+v"(hv[1][4]), "+v"(hv[1][5]), "+v"(hv[1][6]), "+v"(hv[1][7]));
        else if (b == 2) asm volatile("s_waitcnt vmcnt(8)"
          : "+v"(hv[2][0]), "+v"(hv[2][1]), "+v"(hv[2][2]), "+v"(hv[2][3]),
            "+v"(hv[2][4]), "+v"(hv[2][5]), "+v"(hv[2][6]), "+v"(hv[2][7]));
        else asm volatile("s_waitcnt vmcnt(0)"
          : "+v"(hv[3][0]), "+v"(hv[3][1]), "+v"(hv[3][2]), "+v"(hv[3][3]),
            "+v"(hv[3][4]), "+v"(hv[3][5]), "+v"(hv[3][6]), "+v"(hv[3][7]));
        #pragma unroll
        for (int i = 0; i < 8; ++i) {
          f32x4 h4 = hv[b][i];
          am[0][b] += wh[i].x * h4.x + wh[i].y * h4.y + wh[i].z * h4.z + wh[i].w * h4.w;
          am[1][b] += wz[i].x * h4.x + wz[i].y * h4.y + wz[i].z * h4.z + wz[i].w * h4.w;
          am[2][b] += fw[i].x * h4.x + fw[i].y * h4.y + fw[i].z * h4.z + fw[i].w * h4.w;
        }
      }
    }
    // ---- reduce over ks within wave (ks bits 0,1 = lane bits 4,5) ----
    #pragma unroll
    for (int m = 0; m < 3; ++m)
      #pragma unroll
      for (int b = 0; b < 4; ++b) {
        am[m][b] += __shfl_xor(am[m][b], 16, 64);
        am[m][b] += __shfl_xor(am[m][b], 32, 64);
      }
    if (lane < 16) {
      #pragma unroll
      for (int m = 0; m < 3; ++m)
        #pragma unroll
        for (int b = 0; b < 4; ++b)
          red[t & 1][w][lane][m * 4 + b] = am[m][b];
    }
    __syncthreads();
    // ---- wave 0: cross-wave reduce + nonlinearity + publish ----
    if (w == 0) {
      float s0 = 0.f, s1 = 0.f, s2 = 0.f;
      #pragma unroll
      for (int ww = 0; ww < 4; ++ww) {
        s0 += red[t & 1][ww][ej][0 + eb];
        s1 += red[t & 1][ww][ej][4 + eb];
        s2 += red[t & 1][ww][ej][8 + eb];
      }
      asm volatile("s_waitcnt vmcnt(0)" : "+v"(pxin), "+v"(pxz));  // t==0 path: xin pending
      float u = pxin + s0;
      float f = tanhf(u);
      float hl = hold + dtv * (f - tauv * hold);
      float zv = sigm_f(pxz + s1);
      float slow = (1.f - zv) * hold + zv * hl;
      float hnv = slow + s2;
      hold = hnv;
      float* dst = hn + bglob * 512 + ejg;
      asm volatile("global_store_dword %0, %1, off sc0 sc1" :: "v"(dst), "v"(hnv) : "memory");
      asm volatile("s_waitcnt vmcnt(0)" ::: "memory");             // h visible before flag
      if (tid == 0)
        __hip_atomic_store(grpflags + c * 16, t + 1, __ATOMIC_RELAXED, __HIP_MEMORY_SCOPE_AGENT);
    }
  }
}

// ---------------- pred_error_norm ----------------
__global__ __launch_bounds__(256) void pred_k(const float* __restrict__ hA,
                                              const float* __restrict__ hB,
                                              float* __restrict__ out) {
  const int tid = threadIdx.x;
  float s = 0.f;
  for (int i = tid; i < H_ * B_; i += 256) {
    float a = __hip_atomic_load((const float*)&hA[i], __ATOMIC_RELAXED, __HIP_MEMORY_SCOPE_AGENT);
    float b = __hip_atomic_load((const float*)&hB[i], __ATOMIC_RELAXED, __HIP_MEMORY_SCOPE_AGENT);
    float d = a - b;
    s += d * d;
  }
  #pragma unroll
  for (int m = 1; m < 64; m <<= 1) s += __shfl_xor(s, m, 64);
  __shared__ float r8[4];
  if ((tid & 63) == 0) r8[tid >> 6] = s;
  __syncthreads();
  if (tid == 0) out[0] = sqrtf((r8[0] + r8[1] + r8[2] + r8[3]) * (1.f / (H_ * B_)));
}

// ---------------- LayerNorm over h_last ([32][512] row-major) ----------------
__global__ __launch_bounds__(256) void ln_k(const float* __restrict__ h0,
                                            const float* __restrict__ g,
                                            const float* __restrict__ be,
                                            float* __restrict__ hln,        // [32][512]
                                            float* __restrict__ outh) {
  const int b = blockIdx.x, tid = threadIdx.x;
  float v0 = __hip_atomic_load((const float*)&h0[b * 512 + tid], __ATOMIC_RELAXED, __HIP_MEMORY_SCOPE_AGENT);
  float v1 = __hip_atomic_load((const float*)&h0[b * 512 + tid + 256], __ATOMIC_RELAXED, __HIP_MEMORY_SCOPE_AGENT);
  float s = v0 + v1;
  #pragma unroll
  for (int m = 1; m < 64; m <<= 1) s += __shfl_xor(s, m, 64);
  __shared__ float r8[8];
  if ((tid & 63) == 0) r8[tid >> 6] = s;
  __syncthreads();
  float mu = (r8[0] + r8[1] + r8[2] + r8[3]) * (1.f / 512.f);
  float d0 = v0 - mu, d1 = v1 - mu;
  float s2 = d0 * d0 + d1 * d1;
  #pragma unroll
  for (int m = 1; m < 64; m <<= 1) s2 += __shfl_xor(s2, m, 64);
  if ((tid & 63) == 0) r8[4 + (tid >> 6)] = s2;
  __syncthreads();
  float var = (r8[4] + r8[5] + r8[6] + r8[7]) * (1.f / 512.f);
  float inv = rsqrtf(var + 1e-5f);
  float y0 = d0 * inv * g[tid] + be[tid];
  float y1 = d1 * inv * g[tid + 256] + be[tid + 256];
  hln[b * 512 + tid] = y0;
  hln[b * 512 + tid + 256] = y1;
  outh[b * 512 + tid] = y0;
  outh[b * 512 + tid + 256] = y1;
}

// ---------------- LM head: logits = hln @ Wlm^T + blm ----------------
__global__ __launch_bounds__(256, 2) void logits_k(const float* __restrict__ hln,
                                                   const float* __restrict__ Wlm,
                                                   const float* __restrict__ blm,
                                                   float* __restrict__ out) {
  __shared__ float hs[32 * 513];
  const int tid = threadIdx.x;
  for (int idx = tid; idx < 16384; idx += 256) {
    int b = idx >> 9, k = idx & 511;
    hs[b * 513 + k] = hln[idx];
  }
  __syncthreads();
  const int lane = tid & 63, w = tid >> 6;
  const int b = lane & 31, kh = lane >> 5;
  const float* hb = &hs[b * 513 + kh * 256];
  const int vbase = blockIdx.x * 64 + w * 16;
  for (int r4 = 0; r4 < 16; r4 += 4) {
    int v = vbase + r4;
    int v0i = (v + 0 < V_) ? v + 0 : V_ - 1;
    int v1i = (v + 1 < V_) ? v + 1 : V_ - 1;
    int v2i = (v + 2 < V_) ? v + 2 : V_ - 1;
    int v3i = (v + 3 < V_) ? v + 3 : V_ - 1;
    const float4* w0 = (const float4*)&Wlm[(size_t)v0i * 512 + kh * 256];
    const float4* w1 = (const float4*)&Wlm[(size_t)v1i * 512 + kh * 256];
    const float4* w2 = (const float4*)&Wlm[(size_t)v2i * 512 + kh * 256];
    const float4* w3 = (const float4*)&Wlm[(size_t)v3i * 512 + kh * 256];
    float a0 = 0.f, a1 = 0.f, a2 = 0.f, a3 = 0.f;
    #pragma unroll 8
    for (int q = 0; q < 64; ++q) {
      float h0 = hb[q * 4 + 0], h1 = hb[q * 4 + 1], h2 = hb[q * 4 + 2], h3 = hb[q * 4 + 3];
      float4 x;
      x = w0[q]; a0 += x.x * h0 + x.y * h1 + x.z * h2 + x.w * h3;
      x = w1[q]; a1 += x.x * h0 + x.y * h1 + x.z * h2 + x.w * h3;
      x = w2[q]; a2 += x.x * h0 + x.y * h1 + x.z * h2 + x.w * h3;
      x = w3[q]; a3 += x.x * h0 + x.y * h1 + x.z * h2 + x.w * h3;
    }
    a0 += __shfl_xor(a0, 32, 64);
    a1 += __shfl_xor(a1, 32, 64);
    a2 += __shfl_xor(a2, 32, 64);
    a3 += __shfl_xor(a3, 32, 64);
    if (lane < 32) {
      if (v + 0 < V_) out[(size_t)b * V_ + v + 0] = a0 + blm[v + 0];
      if (v + 1 < V_) out[(size_t)b * V_ + v + 1] = a1 + blm[v + 1];
      if (v + 2 < V_) out[(size_t)b * V_ + v + 2] = a2 + blm[v + 2];
      if (v + 3 < V_) out[(size_t)b * V_ + v + 3] = a3 + blm[v + 3];
    }
  }
}

extern "C" void kernel_launch(void* const* d_in, const int* in_sizes, int n_in,
                              void* d_out, int out_size, void* d_ws, size_t ws_size,
                              hipStream_t stream) {
  const int*   ids     = (const int*)d_in[0];
  const float* emb     = (const float*)d_in[1];
  const float* Wq      = (const float*)d_in[2];
  const float* Wk      = (const float*)d_in[3];
  const float* Wv      = (const float*)d_in[4];
  // d_in[5] = Wo (unused in forward)
  const float* Wg      = (const float*)d_in[6];
  const float* bg      = (const float*)d_in[7];
  const float* W_in    = (const float*)d_in[8];
  const float* b_in    = (const float*)d_in[9];
  const float* W_h     = (const float*)d_in[10];
  const float* log_tau = (const float*)d_in[11];
  const float* log_dt  = (const float*)d_in[12];
  const float* W_zx    = (const float*)d_in[13];
  const float* b_zx    = (const float*)d_in[14];
  const float* W_zh    = (const float*)d_in[15];
  const float* fast_W  = (const float*)d_in[16];
  const float* ln_g    = (const float*)d_in[17];
  const float* ln_b    = (const float*)d_in[18];
  const float* Wlm     = (const float*)d_in[19];
  const float* blm     = (const float*)d_in[20];

  char* ws = (char*)d_ws;
  float* x0    = (float*)(ws + OFF_X0);
  float* x1    = (float*)(ws + OFF_X1);
  float* xzb   = (float*)(ws + OFF_XZ);
  float* rbuf  = (float*)(ws + OFF_RBUF);
  float* ksum  = (float*)(ws + OFF_KSUM);
  float* kvsum = (float*)(ws + OFF_KVSUM);
  int*   flags = (int*)(ws + OFF_FLAGS);
  float* hbuf  = (float*)(ws + OFF_HBUF);
  float* hln   = (float*)(ws + OFF_HLN);
  float* out   = (float*)d_out;

  const int nzero = (int)ZERO_F4;
  zero_k<<<dim3((nzero + 255) / 256), dim3(256), 0, stream>>>((float4*)(ws + OFF_SMALL), nzero);
  embed_k<<<dim3(BT_ * 128 / 256), dim3(256), 0, stream>>>(ids, emb, x0);

  dim3 gg(BT_ / 64, 8);
  gemm_k<0><<<gg, dim3(256), 0, stream>>>(x0, Wk, Wv, nullptr, nullptr, nullptr, ksum, kvsum);
  gemm_k<1><<<gg, dim3(256), 0, stream>>>(x0, Wq, nullptr, nullptr, kvsum, ksum, rbuf, nullptr);
  gemm_k<2><<<gg, dim3(256), 0, stream>>>(x0, Wg, nullptr, bg, rbuf, x0, x1, nullptr);
  gemm_k<3><<<gg, dim3(256), 0, stream>>>(x1, W_in, nullptr, b_in, nullptr, nullptr, x0, nullptr);
  gemm_k<3><<<gg, dim3(256), 0, stream>>>(x1, W_zx, nullptr, b_zx, nullptr, nullptr, xzb, nullptr);

  scan_k<<<dim3(256), dim3(256), 0, stream>>>(x0, xzb, W_h, W_zh, fast_W, log_tau, log_dt, hbuf, flags);

  // h_last = hbuf[0] (t=2047 writes parity 0), h_prev = hbuf[1]
  pred_k<<<dim3(1), dim3(256), 0, stream>>>(hbuf, hbuf + B_ * H_, out + (size_t)B_ * V_ + (size_t)B_ * H_);
  ln_k<<<dim3(32), dim3(256), 0, stream>>>(hbuf, ln_g, ln_b, hln, out + (size_t)B_ * V_);
  logits_k<<<dim3((V_ + 63) / 64), dim3(256), 0, stream>>>(hln, Wlm, blm, out);
}